// Round 6
// baseline (299.374 us; speedup 1.0000x reference)
//
#include <hip/hip_runtime.h>
#include <cmath>

#define NTOK 65536
#define DMOD 1024
#define NEXP 64
#define TOPK 8
#define KCH  64                  // k-chunk staged in LDS
#define STR  65                  // LDS row stride (floats)

// token_mask may arrive as 1-byte bool or int32; sniff from the first word.
__device__ __forceinline__ bool tok_mask(const void* tm, int t, int mmode) {
    return mmode == 0 ? (((const unsigned char*)tm)[t] != 0)
                      : (((const unsigned int*)tm)[t] != 0u);
}

__global__ __launch_bounds__(256, 4)
void router_v6(const float* __restrict__ h,
               const float* __restrict__ W,
               const void* __restrict__ tmask,
               float* __restrict__ out)
{
    __shared__ float h_s[64][STR];            // 16.6 KB; pb aliases after compute
    __shared__ float w_s[64][STR];            // 16.6 KB; ls aliases after compute
    __shared__ unsigned long long mb[64];

    const int tid  = threadIdx.x;
    const int lane = tid & 63;
    const int wave = tid >> 6;
    const int tt   = tid & 15;                // token group (rows tt*4 .. tt*4+3)
    const int ee   = tid >> 4;                // expert group (rows ee*4 .. ee*4+3)
    const int t0   = blockIdx.x * 64;

    const unsigned int w0 = *(const unsigned int*)tmask;
    const int mmode = (w0 == 0x01010101u) ? 0 : 1;

    // strict sequential fp32 FMA per output, k ascending (np-ref-matching order)
    float acc[4][4];
#pragma unroll
    for (int i = 0; i < 4; ++i)
#pragma unroll
        for (int j = 0; j < 4; ++j) acc[i][j] = 0.f;

    const int sr = tid >> 4;                  // staging row base 0..15
    const int sc = (tid & 15) * 4;            // staging col 0..60

    // ---- prologue: issue chunk-0 staging loads into registers ----
    float4 hreg[4], wreg[4];
#pragma unroll
    for (int p = 0; p < 4; ++p) {
        const int row = sr + p * 16;
        hreg[p] = *reinterpret_cast<const float4*>(h + (size_t)(t0 + row) * DMOD + sc);
        wreg[p] = *reinterpret_cast<const float4*>(W + ((size_t)row << 10) + sc);
    }

    for (int kc = 0; kc < DMOD; kc += KCH) {
        // ---- write staged registers to LDS ----
#pragma unroll
        for (int p = 0; p < 4; ++p) {
            const int row = sr + p * 16;
            *reinterpret_cast<float4*>(&h_s[row][sc]) = hreg[p];
            *reinterpret_cast<float4*>(&w_s[row][sc]) = wreg[p];
        }
        __syncthreads();

        // ---- issue NEXT chunk's global loads now; latency hides under compute ----
        if (kc + KCH < DMOD) {
            const int kn = kc + KCH;
#pragma unroll
            for (int p = 0; p < 4; ++p) {
                const int row = sr + p * 16;
                hreg[p] = *reinterpret_cast<const float4*>(h + (size_t)(t0 + row) * DMOD + kn + sc);
                wreg[p] = *reinterpret_cast<const float4*>(W + ((size_t)row << 10) + kn + sc);
            }
        }

        // ---- compute: 4 tokens x 4 experts, FULLY unrolled (immediate LDS offsets) ----
#pragma unroll
        for (int k = 0; k < KCH; k += 4) {
            float4 hv[4], wv[4];
#pragma unroll
            for (int i = 0; i < 4; ++i)
                hv[i] = *reinterpret_cast<const float4*>(&h_s[tt * 4 + i][k]);
#pragma unroll
            for (int j = 0; j < 4; ++j)
                wv[j] = *reinterpret_cast<const float4*>(&w_s[ee * 4 + j][k]);
#pragma unroll
            for (int i = 0; i < 4; ++i) {
#pragma unroll
                for (int j = 0; j < 4; ++j) {
                    float a = acc[i][j];
                    a = fmaf(hv[i].x, wv[j].x, a);
                    a = fmaf(hv[i].y, wv[j].y, a);
                    a = fmaf(hv[i].z, wv[j].z, a);
                    a = fmaf(hv[i].w, wv[j].w, a);
                    acc[i][j] = a;
                }
            }
        }
        __syncthreads();
    }

    // ---- stage logits to LDS (ls aliases w_s — dead after last barrier) ----
    float (*ls)[STR] = w_s;
    float (*pb)[STR] = h_s;

#pragma unroll
    for (int i = 0; i < 4; ++i)
#pragma unroll
        for (int j = 0; j < 4; ++j)
            ls[tt * 4 + i][ee * 4 + j] = acc[i][j];

    __syncthreads();

    const size_t P = (size_t)NTOK * NEXP;
    float* __restrict__ o_mask = out;
    float* __restrict__ o_prob = out + P;
    float* __restrict__ o_lc   = out + 2 * P;
    float* __restrict__ o_lsl  = out + 3 * P;
    const size_t base = (size_t)t0 * NEXP;

    // ---- coalesced writes of logits_clean / logits_sel ----
#pragma unroll
    for (int i = 0; i < 16; ++i) {
        const int f = i * 256 + tid;
        const int t = f >> 6, e = f & 63;
        const float lv = ls[t][e];
        const bool tmt = tok_mask(tmask, t0 + t, mmode);
        o_lc[base + f]  = lv;
        o_lsl[base + f] = tmt ? lv : -INFINITY;
    }

    // ---- epilogue: wave0, one token per lane; 8-pass selection-sort top-k ----
    if (wave == 0) {
        const int lt = lane;
        const bool tm = tok_mask(tmask, t0 + lt, mmode);

        unsigned long long bits = 0ULL;
        float m0 = -INFINITY;
        for (int r = 0; r < TOPK; ++r) {
            float bv = -INFINITY; int bi = 0;
            for (int e = 0; e < 64; ++e) {
                if ((bits >> e) & 1ULL) continue;
                const float x = ls[lt][e];
                if (x > bv) { bv = x; bi = e; }
            }
            bits |= 1ULL << bi;
            if (r == 0) m0 = bv;
        }

        float ssum = 0.f;
        for (int e = 0; e < 64; ++e)
            if ((bits >> e) & 1ULL) ssum += expf(ls[lt][e] - m0);
        const float inv = 1.0f / ssum;
        for (int e = 0; e < 64; ++e) {
            const bool sel = ((bits >> e) & 1ULL) != 0ULL;
            pb[lt][e] = (tm && sel) ? expf(ls[lt][e] - m0) * inv : 0.f;
        }
        mb[lt] = tm ? bits : 0ULL;
    }

    __syncthreads();

    // ---- coalesced writes of probs / mask ----
#pragma unroll
    for (int i = 0; i < 16; ++i) {
        const int f = i * 256 + tid;
        const int t = f >> 6, e = f & 63;
        o_prob[base + f] = pb[t][e];
        o_mask[base + f] = (float)((mb[t] >> e) & 1ULL);
    }
}

extern "C" void kernel_launch(void* const* d_in, const int* in_sizes, int n_in,
                              void* d_out, int out_size, void* d_ws, size_t ws_size,
                              hipStream_t stream)
{
    const float* h = (const float*)d_in[0];
    const float* W = (const float*)d_in[1];
    const void*  tmask = (const void*)d_in[2];
    float* out = (float*)d_out;

    hipLaunchKernelGGL(router_v6, dim3(NTOK / 64), dim3(256), 0, stream,
                       h, W, tmask, out);
}

// Round 7
// 276.474 us; speedup vs baseline: 1.0828x; 1.0828x over previous
//
#include <hip/hip_runtime.h>
#include <cmath>

#define NTOK 65536
#define DMOD 1024
#define NEXP 64
#define TOPK 8
#define KCH  32                  // k-chunk (W in registers per chunk)
#define TPW  16                  // tokens per wave
#define NCH  (DMOD / KCH)

// token_mask may arrive as 1-byte bool or int32; sniff from the first word.
__device__ __forceinline__ bool tok_mask(const void* tm, int t, int mmode) {
    return mmode == 0 ? (((const unsigned char*)tm)[t] != 0)
                      : (((const unsigned int*)tm)[t] != 0u);
}

__global__ __launch_bounds__(256, 4)
void router_v7(const float* __restrict__ h,
               const float* __restrict__ W,
               const void* __restrict__ tmask,
               float* __restrict__ out)
{
    __shared__ float w_s[2][64][33];          // double-buffered W chunk (16.9 KB)
    __shared__ float ls[64][65];              // logits tile (16.6 KB)
    __shared__ float sm_m0[64], sm_inv[64];
    __shared__ unsigned long long mb[64];

    const int tid  = threadIdx.x;
    const int lane = tid & 63;                // = expert index
    const int wave = __builtin_amdgcn_readfirstlane(tid >> 6);
    const int t0   = blockIdx.x * 64;
    const int tokw = t0 + wave * TPW;         // wave-uniform first token

    const unsigned int mw = *(const unsigned int*)tmask;
    const int mmode = (mw == 0x01010101u) ? 0 : 1;

    // per-thread accumulators: 16 tokens x 1 expert; strict sequential-k fmaf
    float acc[TPW];
#pragma unroll
    for (int i = 0; i < TPW; ++i) acc[i] = 0.f;

    // W staging map: 64 rows x 32 cols; thread -> row tid>>2, cols (tid&3)*8..+7
    const int swr = tid >> 2;
    const int swc = (tid & 3) * 8;

    // prologue: stage chunk 0 into buffer 0
    {
        const float* wp = W + ((size_t)swr << 10) + swc;
        *reinterpret_cast<float4*>(&w_s[0][swr][swc])     = *reinterpret_cast<const float4*>(wp);
        *reinterpret_cast<float4*>(&w_s[0][swr][swc + 4]) = *reinterpret_cast<const float4*>(wp + 4);
    }
    __syncthreads();

    for (int c = 0; c < NCH; ++c) {
        const int kc = c * KCH;
        const int cur = c & 1;

        // ---- this chunk's W row into registers (lane = expert; 2-way banks, free) ----
        float4 wr[8];
#pragma unroll
        for (int j = 0; j < 8; ++j)
            wr[j] = *reinterpret_cast<const float4*>(&w_s[cur][lane][j * 4]);

        // ---- issue next chunk's global W loads NOW (write to LDS after compute) ----
        float4 g0, g1;
        const bool more = (c + 1 < NCH);
        if (more) {
            const float* wp = W + ((size_t)swr << 10) + kc + KCH + swc;
            g0 = *reinterpret_cast<const float4*>(wp);
            g1 = *reinterpret_cast<const float4*>(wp + 4);
        }

        // ---- compute: 16 tokens, h via wave-uniform (scalar-pipe) loads ----
#pragma unroll
        for (int i = 0; i < TPW; ++i) {
            const float* hp = h + ((size_t)(tokw + i) << 10) + kc;   // uniform addr
            const float4 h0 = *reinterpret_cast<const float4*>(hp);
            const float4 h1 = *reinterpret_cast<const float4*>(hp + 4);
            const float4 h2 = *reinterpret_cast<const float4*>(hp + 8);
            const float4 h3 = *reinterpret_cast<const float4*>(hp + 12);
            const float4 h4 = *reinterpret_cast<const float4*>(hp + 16);
            const float4 h5 = *reinterpret_cast<const float4*>(hp + 20);
            const float4 h6 = *reinterpret_cast<const float4*>(hp + 24);
            const float4 h7 = *reinterpret_cast<const float4*>(hp + 28);
            float a = acc[i];
            a = fmaf(h0.x, wr[0].x, a); a = fmaf(h0.y, wr[0].y, a);
            a = fmaf(h0.z, wr[0].z, a); a = fmaf(h0.w, wr[0].w, a);
            a = fmaf(h1.x, wr[1].x, a); a = fmaf(h1.y, wr[1].y, a);
            a = fmaf(h1.z, wr[1].z, a); a = fmaf(h1.w, wr[1].w, a);
            a = fmaf(h2.x, wr[2].x, a); a = fmaf(h2.y, wr[2].y, a);
            a = fmaf(h2.z, wr[2].z, a); a = fmaf(h2.w, wr[2].w, a);
            a = fmaf(h3.x, wr[3].x, a); a = fmaf(h3.y, wr[3].y, a);
            a = fmaf(h3.z, wr[3].z, a); a = fmaf(h3.w, wr[3].w, a);
            a = fmaf(h4.x, wr[4].x, a); a = fmaf(h4.y, wr[4].y, a);
            a = fmaf(h4.z, wr[4].z, a); a = fmaf(h4.w, wr[4].w, a);
            a = fmaf(h5.x, wr[5].x, a); a = fmaf(h5.y, wr[5].y, a);
            a = fmaf(h5.z, wr[5].z, a); a = fmaf(h5.w, wr[5].w, a);
            a = fmaf(h6.x, wr[6].x, a); a = fmaf(h6.y, wr[6].y, a);
            a = fmaf(h6.z, wr[6].z, a); a = fmaf(h6.w, wr[6].w, a);
            a = fmaf(h7.x, wr[7].x, a); a = fmaf(h7.y, wr[7].y, a);
            a = fmaf(h7.z, wr[7].z, a); a = fmaf(h7.w, wr[7].w, a);
            acc[i] = a;
        }

        // ---- write staged next-chunk W into the other buffer; one barrier/chunk ----
        if (more) {
            *reinterpret_cast<float4*>(&w_s[cur ^ 1][swr][swc])     = g0;
            *reinterpret_cast<float4*>(&w_s[cur ^ 1][swr][swc + 4]) = g1;
        }
        __syncthreads();
    }

    // ---- stage logits: lane e writes its 16 tokens' logits (2-way banks) ----
#pragma unroll
    for (int i = 0; i < TPW; ++i) ls[wave * TPW + i][lane] = acc[i];

    __syncthreads();

    const size_t P = (size_t)NTOK * NEXP;
    float* __restrict__ o_mask = out;
    float* __restrict__ o_prob = out + P;
    float* __restrict__ o_lc   = out + 2 * P;
    float* __restrict__ o_lsl  = out + 3 * P;
    const size_t base = (size_t)t0 * NEXP;

    // ---- coalesced writes of logits_clean / logits_sel ----
#pragma unroll
    for (int i = 0; i < 16; ++i) {
        const int f = i * 256 + tid;
        const int t = f >> 6, e = f & 63;
        const float lv = ls[t][e];
        const bool tmt = tok_mask(tmask, t0 + t, mmode);
        o_lc[base + f]  = lv;
        o_lsl[base + f] = tmt ? lv : -INFINITY;
    }

    // ---- epilogue: wave0, one token per lane; 8-pass selection-sort top-k ----
    if (wave == 0) {
        const int lt = lane;
        const bool tm = tok_mask(tmask, t0 + lt, mmode);

        unsigned long long bits = 0ULL;
        float m0 = -INFINITY;
        for (int r = 0; r < TOPK; ++r) {
            float bv = -INFINITY; int bi = 0;
            for (int e = 0; e < 64; ++e) {
                if ((bits >> e) & 1ULL) continue;
                const float x = ls[lt][e];
                if (x > bv) { bv = x; bi = e; }
            }
            bits |= 1ULL << bi;
            if (r == 0) m0 = bv;
        }

        float ssum = 0.f;
        for (int e = 0; e < 64; ++e)
            if ((bits >> e) & 1ULL) ssum += expf(ls[lt][e] - m0);

        sm_m0[lt]  = m0;
        sm_inv[lt] = 1.0f / ssum;
        mb[lt] = tm ? bits : 0ULL;            // mb==0 encodes masked token
    }

    __syncthreads();

    // ---- coalesced writes of probs / mask (probs computed on the fly) ----
#pragma unroll
    for (int i = 0; i < 16; ++i) {
        const int f = i * 256 + tid;
        const int t = f >> 6, e = f & 63;
        const unsigned long long bt = mb[t];
        const bool sel = ((bt >> e) & 1ULL) != 0ULL;
        o_prob[base + f] = sel ? expf(ls[t][e] - sm_m0[t]) * sm_inv[t] : 0.f;
        o_mask[base + f] = sel ? 1.0f : 0.0f;
    }
}

extern "C" void kernel_launch(void* const* d_in, const int* in_sizes, int n_in,
                              void* d_out, int out_size, void* d_ws, size_t ws_size,
                              hipStream_t stream)
{
    const float* h = (const float*)d_in[0];
    const float* W = (const float*)d_in[1];
    const void*  tmask = (const void*)d_in[2];
    float* out = (float*)d_out;

    hipLaunchKernelGGL(router_v7, dim3(NTOK / 64), dim3(256), 0, stream,
                       h, W, tmask, out);
}